// Round 1
// baseline (690.607 us; speedup 1.0000x reference)
//
#include <hip/hip_runtime.h>
#include <math.h>

#define NSLC 2
#define NPC 3
#define ETL 4
#define NCHA 4
#define NX 128
#define NY 128
#define NLIN 128
#define NCOL 256
#define NLIN_PE (NLIN / ETL)          // 32
#define M_PER_ECHO (NLIN_PE * NCOL)   // 8192
#define NB (NSLC * NCHA)              // 8

#define MTILE 16        // m-points per block
#define XCHUNK 2        // x-rows staged per chunk

// ---------------------------------------------------------------------------
// Kernel 1: coil[e][b][x][y] = (sum_p D[s,e,p] * image[s,p,x,y]) * smaps[s,c,x,y]
//   b = s*NCHA + c.  Stored as float2 (re, im) in workspace.
// ---------------------------------------------------------------------------
__global__ __launch_bounds__(256) void prep_coil(
    const float* __restrict__ imR, const float* __restrict__ imI,
    const float* __restrict__ smR, const float* __restrict__ smI,
    const float* __restrict__ Dm, float2* __restrict__ coil) {
  int tid = blockIdx.x * blockDim.x + threadIdx.x;  // (s, x, y)
  if (tid >= NSLC * NX * NY) return;
  int y = tid & (NY - 1);
  int x = (tid >> 7) & (NX - 1);
  int s = tid >> 14;

  float ir[NPC], ii[NPC];
#pragma unroll
  for (int p = 0; p < NPC; ++p) {
    int idx = ((s * NPC + p) * NX + x) * NY + y;
    ir[p] = imR[idx];
    ii[p] = imI[idx];
  }
  float sr[NCHA], si[NCHA];
#pragma unroll
  for (int c = 0; c < NCHA; ++c) {
    int idx = ((s * NCHA + c) * NX + x) * NY + y;
    sr[c] = smR[idx];
    si[c] = smI[idx];
  }
#pragma unroll
  for (int e = 0; e < ETL; ++e) {
    float gr = 0.f, gi = 0.f;
#pragma unroll
    for (int p = 0; p < NPC; ++p) {
      float d = Dm[(s * ETL + e) * NPC + p];
      gr += d * ir[p];
      gi += d * ii[p];
    }
#pragma unroll
    for (int c = 0; c < NCHA; ++c) {
      int b = s * NCHA + c;
      float cr = gr * sr[c] - gi * si[c];
      float ci = gr * si[c] + gi * sr[c];
      coil[(e * NB + b) * (NX * NY) + x * NY + y] = make_float2(cr, ci);
    }
  }
}

// ---------------------------------------------------------------------------
// Kernel 2: direct NUDFT.  One block = (echo, tile of MTILE m-points).
//   wave w owns m_local = w*4 .. w*4+3, all 8 b; lanes split the y axis.
//   k[b,m] = sum_{x,y} coil[b,x,y] * ex[m,x] * ey[m,y]
// ---------------------------------------------------------------------------
__global__ __launch_bounds__(256) void radtse_main(
    const float2* __restrict__ coil, const float* __restrict__ traj,
    const float* __restrict__ mask, float* __restrict__ out) {
  __shared__ float2 exT[MTILE][NX];           // 16 KB
  __shared__ float2 eyT[MTILE][NY];           // 16 KB
  __shared__ float2 cT[NB][XCHUNK][NY];       // 16 KB

  int e = blockIdx.x >> 9;        // 512 tiles per echo
  int tile = blockIdx.x & 511;
  int m0 = tile * MTILE;
  int tid = threadIdx.x;
  int w = tid >> 6;
  int lane = tid & 63;

  // Build phase tables: ex[mi][u] = exp(-i kx (u-64)), ey[mi][u] = exp(-i ky (u-64))
  for (int i = tid; i < MTILE * NX; i += 256) {
    int mi = i >> 7;
    int u = i & 127;
    int m = m0 + mi;
    int lin = e * NLIN_PE + (m >> 8);
    int col = m & (NCOL - 1);
    float kx = traj[(lin * NCOL + col) * 2 + 0];
    float ky = traj[(lin * NCOL + col) * 2 + 1];
    float fu = (float)(u - 64);
    float sx, cx, sy, cy;
    __sincosf(kx * fu, &sx, &cx);
    __sincosf(ky * fu, &sy, &cy);
    exT[mi][u] = make_float2(cx, -sx);
    eyT[mi][u] = make_float2(cy, -sy);
  }
  __syncthreads();

  // Hoist ey for this lane's two y values (x-invariant)
  float2 ey[4][2];
#pragma unroll
  for (int mi = 0; mi < 4; ++mi)
#pragma unroll
    for (int yi = 0; yi < 2; ++yi)
      ey[mi][yi] = eyT[w * 4 + mi][lane + 64 * yi];

  float accR[4][8], accI[4][8];
#pragma unroll
  for (int mi = 0; mi < 4; ++mi)
#pragma unroll
    for (int b = 0; b < 8; ++b) {
      accR[mi][b] = 0.f;
      accI[mi][b] = 0.f;
    }

  const float2* cbase = coil + e * NB * NX * NY;

  for (int xc = 0; xc < NX / XCHUNK; ++xc) {
    __syncthreads();  // previous chunk fully consumed
    // stage XCHUNK rows of all 8 coil images: 2048 float2 = 1024 float4
#pragma unroll
    for (int k = 0; k < 4; ++k) {
      int j = tid + k * 256;        // float4 index in [0,1024)
      int f2 = j * 2;               // float2 index
      int b = f2 >> 8;              // 256 float2 per b
      int rem = f2 & 255;           // xr*128 + y
      const float4* src = reinterpret_cast<const float4*>(
          cbase + b * (NX * NY) + xc * (XCHUNK * NY) + rem);
      float4* dst = reinterpret_cast<float4*>(&cT[0][0][0] + b * 256 + rem);
      *dst = *src;
    }
    __syncthreads();

#pragma unroll
    for (int xr = 0; xr < XCHUNK; ++xr) {
      float2 ex[4];
#pragma unroll
      for (int mi = 0; mi < 4; ++mi) ex[mi] = exT[w * 4 + mi][xc * XCHUNK + xr];
#pragma unroll
      for (int yi = 0; yi < 2; ++yi) {
        int y = lane + 64 * yi;
        float2 cv[8];
#pragma unroll
        for (int b = 0; b < 8; ++b) cv[b] = cT[b][xr][y];
#pragma unroll
        for (int mi = 0; mi < 4; ++mi) {
          float2 eyv = ey[mi][yi];
          float wr = ex[mi].x * eyv.x - ex[mi].y * eyv.y;
          float wi = ex[mi].x * eyv.y + ex[mi].y * eyv.x;
#pragma unroll
          for (int b = 0; b < 8; ++b) {
            accR[mi][b] += cv[b].x * wr - cv[b].y * wi;
            accI[mi][b] += cv[b].x * wi + cv[b].y * wr;
          }
        }
      }
    }
  }

  // Wave-level butterfly reduction (all lanes end with totals)
#pragma unroll
  for (int mi = 0; mi < 4; ++mi)
#pragma unroll
    for (int b = 0; b < 8; ++b) {
      float r = accR[mi][b];
      float im = accI[mi][b];
#pragma unroll
      for (int off = 32; off > 0; off >>= 1) {
        r += __shfl_xor(r, off, 64);
        im += __shfl_xor(im, off, 64);
      }
      accR[mi][b] = r;
      accI[mi][b] = im;
    }

  // Predicated writes: lane (mi*8+b) writes output (m, b). Static indices only.
#pragma unroll
  for (int mi = 0; mi < 4; ++mi)
#pragma unroll
    for (int b = 0; b < 8; ++b) {
      if (lane == mi * 8 + b) {
        int m = m0 + w * 4 + mi;
        int lin = e * NLIN_PE + (m >> 8);
        int col = m & (NCOL - 1);
        int s = b >> 2;
        float mv = mask[(s * NLIN + lin) * NCOL + col];
        int oidx = ((b * NLIN + lin) * NCOL + col) * 2;
        out[oidx + 0] = accR[mi][b] * mv;
        out[oidx + 1] = accI[mi][b] * mv;
      }
    }
}

extern "C" void kernel_launch(void* const* d_in, const int* in_sizes, int n_in,
                              void* d_out, int out_size, void* d_ws, size_t ws_size,
                              hipStream_t stream) {
  const float* imR = (const float*)d_in[0];
  const float* imI = (const float*)d_in[1];
  const float* smR = (const float*)d_in[2];
  const float* smI = (const float*)d_in[3];
  const float* Dm = (const float*)d_in[4];
  const float* mask = (const float*)d_in[5];
  const float* traj = (const float*)d_in[6];
  float* out = (float*)d_out;
  float2* coil = (float2*)d_ws;  // 4 MB: [ETL][NB][NX][NY] float2

  prep_coil<<<dim3(NSLC * NX * NY / 256), dim3(256), 0, stream>>>(imR, imI, smR,
                                                                  smI, Dm, coil);
  radtse_main<<<dim3(ETL * (M_PER_ECHO / MTILE)), dim3(256), 0, stream>>>(
      coil, traj, mask, out);
}

// Round 2
// 103.484 us; speedup vs baseline: 6.6735x; 6.6735x over previous
//
#include <hip/hip_runtime.h>
#include <math.h>

#define NSLC 2
#define NPC 3
#define ETL 4
#define NCHA 4
#define NX 128
#define NY 128
#define NLIN 128
#define NCOL 256
#define NLIN_PE 32            // lines per echo
#define NB 8                  // nslc*ncha
#define NROW (NB * NX)        // 1024 GEMM rows per echo
#define KDIM 256              // 2*NY (Re|Im concat)
#define MT 16                 // m-points per block

typedef __attribute__((ext_vector_type(8))) short short8;
typedef __attribute__((ext_vector_type(4))) float float4_t;

static __device__ __forceinline__ unsigned short f2bf(float f) {
  unsigned u = __float_as_uint(f);
  unsigned r = (u + 0x7FFFu + ((u >> 16) & 1u)) >> 16;
  return (unsigned short)r;
}

// ---------------------------------------------------------------------------
// Kernel 1: build A[e][row=(b,x)][k] bf16, k<128: Re(coil), k>=128: Im(coil),
// PRE-SWIZZLED along k:  k_stored = k ^ ((row&7)<<3)   (row&7 == x&7)
// coil = (sum_p D[s,e,p]*image[s,p,x,y]) * smaps[s,c,x,y]
// ---------------------------------------------------------------------------
__global__ __launch_bounds__(256) void prep_coil(
    const float* __restrict__ imR, const float* __restrict__ imI,
    const float* __restrict__ smR, const float* __restrict__ smI,
    const float* __restrict__ Dm, unsigned short* __restrict__ A) {
  int tid = blockIdx.x * blockDim.x + threadIdx.x;  // (s, x, y)
  if (tid >= NSLC * NX * NY) return;
  int y = tid & (NY - 1);
  int x = (tid >> 7) & (NX - 1);
  int s = tid >> 14;

  float ir[NPC], ii[NPC];
#pragma unroll
  for (int p = 0; p < NPC; ++p) {
    int idx = ((s * NPC + p) * NX + x) * NY + y;
    ir[p] = imR[idx];
    ii[p] = imI[idx];
  }
  float sr[NCHA], si[NCHA];
#pragma unroll
  for (int c = 0; c < NCHA; ++c) {
    int idx = ((s * NCHA + c) * NX + x) * NY + y;
    sr[c] = smR[idx];
    si[c] = smI[idx];
  }
  int sw = (x & 7) << 3;
#pragma unroll
  for (int e = 0; e < ETL; ++e) {
    float gr = 0.f, gi = 0.f;
#pragma unroll
    for (int p = 0; p < NPC; ++p) {
      float d = Dm[(s * ETL + e) * NPC + p];
      gr += d * ir[p];
      gi += d * ii[p];
    }
#pragma unroll
    for (int c = 0; c < NCHA; ++c) {
      int row = (s * NCHA + c) * NX + x;
      float cr = gr * sr[c] - gi * si[c];
      float ci = gr * si[c] + gi * sr[c];
      unsigned short* dst = A + (((e * NROW + row)) << 8);
      dst[y ^ sw] = f2bf(cr);
      dst[(128 + y) ^ sw] = f2bf(ci);
    }
  }
}

// ---------------------------------------------------------------------------
// Kernel 2: MFMA NUDFT. Block = (echo, 16 m-points), 4 waves.
//  GEMM: T[row, n] = sum_k A[row][k] * B[k][n], rows=(b,x), K=256,
//        n<16: Tr(m=n) with B=[cos; +sin]; n>=16: Ti with B=[-sin; cos]
//  fused phase-2: k[b,m] += Tr*exr - Ti*exi  (+i ...)
// ---------------------------------------------------------------------------
__global__ __launch_bounds__(256) void radtse_mfma(
    const unsigned short* __restrict__ A, const float* __restrict__ traj,
    const float* __restrict__ mask, float* __restrict__ out) {
  __shared__ unsigned short Bl[32 * 256];  // 16 KB, swizzled [col][k]
  __shared__ float exT[128][16][2];        // 16 KB  (x, m, re/im)
  __shared__ unsigned short Al[4][4096];   // 32 KB: per-wave 8 KB A tile

  const int tid = threadIdx.x;
  const int w = tid >> 6;
  const int lane = tid & 63;
  const int e = blockIdx.x >> 9;
  const int m0 = (blockIdx.x & 511) << 4;
  const int lin = e * NLIN_PE + (m0 >> 8);  // all 16 m share one line

  // ---- build B (threads 0..127) and exT (threads 128..255) ----
  if (tid < 128) {
    const int n = tid >> 3;              // m-local 0..15
    const int kb = (tid & 7) * 32;       // k chunk base
    const int col = (m0 + n) & (NCOL - 1);
    const float ky = traj[(lin * NCOL + col) * 2 + 1];
    const int sw = (n & 7) << 4;
#pragma unroll
    for (int c8 = 0; c8 < 4; ++c8) {
      short8 v1, v2;
#pragma unroll
      for (int j = 0; j < 8; ++j) {
        int k = kb + c8 * 8 + j;
        float th = ky * (float)((k & 127) - 64);
        float sn, cs;
        __sincosf(th, &sn, &cs);
        float g1 = (k < 128) ? cs : sn;    // Tr col: [Eyr ; -Eyi] = [cos; +sin]
        float g2 = (k < 128) ? -sn : cs;   // Ti col: [Eyi ; Eyr]  = [-sin; cos]
        v1[j] = (short)f2bf(g1);
        v2[j] = (short)f2bf(g2);
      }
      int kbyte = (kb + c8 * 8) * 2;
      *(short8*)((char*)Bl + n * 512 + (kbyte ^ sw)) = v1;
      *(short8*)((char*)Bl + (n + 16) * 512 + (kbyte ^ sw)) = v2;
    }
  } else {
    const int t2 = tid - 128;
    const int m = t2 & 15;
    const int xb = (t2 >> 4) * 16;
    const int col = (m0 + m) & (NCOL - 1);
    const float kx = traj[(lin * NCOL + col) * 2 + 0];
#pragma unroll
    for (int j = 0; j < 16; ++j) {
      int x = xb + j;
      float ph = kx * (float)(x - 64);
      float sn, cs;
      __sincosf(ph, &sn, &cs);
      exT[x][m][0] = cs;
      exT[x][m][1] = -sn;
    }
  }
  __syncthreads();

  // ---- hoist B fragments (per wave: 2 col-tiles x 8 K-steps) ----
  const int ncol_lo = lane & 15;
  const int sub = (lane >> 4) * 16;  // byte offset of k-slice in 64B group
  short8 bfr[2][8];
#pragma unroll
  for (int ct = 0; ct < 2; ++ct) {
    int coln = ct * 16 + ncol_lo;
    int sw = (coln & 7) << 4;
#pragma unroll
    for (int kk = 0; kk < 8; ++kk) {
      int byte = coln * 512 + ((kk * 64 + sub) ^ sw);
      bfr[ct][kk] = *(const short8*)((const char*)Bl + byte);
    }
  }

  float kr[8], ki[8];
#pragma unroll
  for (int b = 0; b < 8; ++b) {
    kr[b] = 0.f;
    ki[b] = 0.f;
  }

  const unsigned short* Ag = A + ((e * NROW) << 8);
  const int arow = lane & 15;
  const int asw = (arow & 7) << 4;
  const int xsub = (lane >> 4) * 4;  // C/D row group

#pragma unroll
  for (int i = 0; i < 16; ++i) {
    const int rt = w + i * 4;  // row-tile 0..63 (16 rows each), b = rt>>3
    const int b = i >> 1;      // compile-time constant per unrolled iter
    // wait: my previous tile's ds_reads must be done before overwriting
    asm volatile("s_waitcnt lgkmcnt(0)" ::: "memory");
    // stage 16 rows x 256 k bf16 = 8 KB into my private LDS buffer
    const unsigned short* gsrc = Ag + ((rt * 16) << 8) + lane * 8;
#pragma unroll
    for (int j = 0; j < 8; ++j) {
      __builtin_amdgcn_global_load_lds(
          (const __attribute__((address_space(1))) unsigned int*)(gsrc + j * 512),
          (__attribute__((address_space(3))) unsigned int*)(&Al[w][j * 512]), 16,
          0, 0);
    }
    asm volatile("s_waitcnt vmcnt(0)" ::: "memory");

    short8 afr[8];
#pragma unroll
    for (int kk = 0; kk < 8; ++kk) {
      int byte = arow * 512 + ((kk * 64 + sub) ^ asw);
      afr[kk] = *(const short8*)((const char*)&Al[w][0] + byte);
    }
    float4_t accR = {0.f, 0.f, 0.f, 0.f};
    float4_t accI = {0.f, 0.f, 0.f, 0.f};
#pragma unroll
    for (int kk = 0; kk < 8; ++kk) {
      accR = __builtin_amdgcn_mfma_f32_16x16x32_bf16(afr[kk], bfr[0][kk], accR,
                                                     0, 0, 0);
      accI = __builtin_amdgcn_mfma_f32_16x16x32_bf16(afr[kk], bfr[1][kk], accI,
                                                     0, 0, 0);
    }
    // fused phase-2: x-phase reduction. x = (rt&7)*16 + xsub + r, m = ncol_lo
    const int xbase = (rt & 7) * 16 + xsub;
#pragma unroll
    for (int r = 0; r < 4; ++r) {
      float exr = exT[xbase + r][ncol_lo][0];
      float exi = exT[xbase + r][ncol_lo][1];
      kr[b] += accR[r] * exr - accI[r] * exi;
      ki[b] += accR[r] * exi + accI[r] * exr;
    }
  }

  // ---- reduce & combine ----
  __syncthreads();  // everyone done reading their Al tile
  float* comb = (float*)&Al[0][0];  // reuse: 4 waves x 16 m x 8 b x 2 = 4 KB
#pragma unroll
  for (int b = 0; b < 8; ++b) {
    float r = kr[b], im = ki[b];
    r += __shfl_xor(r, 16, 64);
    r += __shfl_xor(r, 32, 64);
    im += __shfl_xor(im, 16, 64);
    im += __shfl_xor(im, 32, 64);
    if (lane < 16) {
      comb[((w * 16 + lane) * 8 + b) * 2 + 0] = r;
      comb[((w * 16 + lane) * 8 + b) * 2 + 1] = im;
    }
  }
  __syncthreads();
  {
    const int m_l = tid >> 4;
    const int b = (tid >> 1) & 7;
    const int ri = tid & 1;
    float v = 0.f;
#pragma unroll
    for (int ww = 0; ww < 4; ++ww) v += comb[((ww * 16 + m_l) * 8 + b) * 2 + ri];
    const int m = m0 + m_l;
    const int col = m & (NCOL - 1);
    const int s = b >> 2;
    const float mv = mask[(s * NLIN + lin) * NCOL + col];
    out[((b * NLIN + lin) * NCOL + col) * 2 + ri] = v * mv;
  }
}

extern "C" void kernel_launch(void* const* d_in, const int* in_sizes, int n_in,
                              void* d_out, int out_size, void* d_ws, size_t ws_size,
                              hipStream_t stream) {
  const float* imR = (const float*)d_in[0];
  const float* imI = (const float*)d_in[1];
  const float* smR = (const float*)d_in[2];
  const float* smI = (const float*)d_in[3];
  const float* Dm = (const float*)d_in[4];
  const float* mask = (const float*)d_in[5];
  const float* traj = (const float*)d_in[6];
  float* out = (float*)d_out;
  unsigned short* A = (unsigned short*)d_ws;  // 2 MB: [ETL][1024][256] bf16

  prep_coil<<<dim3(NSLC * NX * NY / 256), dim3(256), 0, stream>>>(imR, imI, smR,
                                                                  smI, Dm, A);
  radtse_mfma<<<dim3(ETL * 512), dim3(256), 0, stream>>>(A, traj, mask, out);
}

// Round 3
// 65.654 us; speedup vs baseline: 10.5190x; 1.5762x over previous
//
#include <hip/hip_runtime.h>
#include <math.h>

#define NSLC 2
#define NPC 3
#define ETL 4
#define NCHA 4
#define NX 128
#define NY 128
#define NLIN 128
#define NCOL 256
#define NLIN_PE 32            // lines per echo
#define NB 8                  // nslc*ncha
#define NROW 1024             // GEMM rows per echo
#define NTILE 64              // 16-row tiles per echo

typedef __attribute__((ext_vector_type(8))) short short8;
typedef __attribute__((ext_vector_type(4))) float float4_t;

static __device__ __forceinline__ unsigned short f2bf(float f) {
  unsigned u = __float_as_uint(f);
  unsigned r = (u + 0x7FFFu + ((u >> 16) & 1u)) >> 16;
  return (unsigned short)r;
}

// ---------------------------------------------------------------------------
// A layout (bf16 elements): addr = (e*64 + rt)*4096 + g*128 + r*8 + j
//   row = rt*16 + r  (row = b*NX + x, so r = x & 15)
//   k   = g*8 + j    (k < 128: Re(coil) at y=k ; k >= 128: Im(coil) at y=k-128)
// This makes the MFMA A-fragment ds_read contiguous (lane*16B) — conflict-free
// — while global_load_lds stages each 8KB row-tile linearly.
// ---------------------------------------------------------------------------
__global__ __launch_bounds__(256) void prep_coil(
    const float* __restrict__ imR, const float* __restrict__ imI,
    const float* __restrict__ smR, const float* __restrict__ smI,
    const float* __restrict__ Dm, unsigned short* __restrict__ A) {
  int tid = blockIdx.x * blockDim.x + threadIdx.x;  // (s, x, y)
  if (tid >= NSLC * NX * NY) return;
  int y = tid & (NY - 1);
  int x = (tid >> 7) & (NX - 1);
  int s = tid >> 14;

  float ir[NPC], ii[NPC];
#pragma unroll
  for (int p = 0; p < NPC; ++p) {
    int idx = ((s * NPC + p) * NX + x) * NY + y;
    ir[p] = imR[idx];
    ii[p] = imI[idx];
  }
  float sr[NCHA], si[NCHA];
#pragma unroll
  for (int c = 0; c < NCHA; ++c) {
    int idx = ((s * NCHA + c) * NX + x) * NY + y;
    sr[c] = smR[idx];
    si[c] = smI[idx];
  }
#pragma unroll
  for (int e = 0; e < ETL; ++e) {
    float gr = 0.f, gi = 0.f;
#pragma unroll
    for (int p = 0; p < NPC; ++p) {
      float d = Dm[(s * ETL + e) * NPC + p];
      gr += d * ir[p];
      gi += d * ii[p];
    }
#pragma unroll
    for (int c = 0; c < NCHA; ++c) {
      int row = (s * NCHA + c) * NX + x;
      int rt = row >> 4;
      float cr = gr * sr[c] - gi * si[c];
      float ci = gr * si[c] + gi * sr[c];
      unsigned short* dst = A + (e * NTILE + rt) * 4096 + (row & 15) * 8 + (y & 7);
      dst[(y >> 3) * 128] = f2bf(cr);
      dst[(16 + (y >> 3)) * 128] = f2bf(ci);
    }
  }
}

// ---------------------------------------------------------------------------
// Main: block = (echo, 16 m-points), 4 waves. Per wave: loop 16 row-tiles
// (double-buffered 8KB LDS, counted vmcnt), 16 MFMA per tile, fused x-phase
// fold with register-resident ex factors.
// ---------------------------------------------------------------------------
__global__ __launch_bounds__(256) void radtse_mfma(
    const unsigned short* __restrict__ A, const float* __restrict__ traj,
    const float* __restrict__ mask, float* __restrict__ out) {
  __shared__ __align__(16) char lds[65536];  // 4 waves x 2 x 8KB (B + combine reuse)

  const int tid = threadIdx.x;
  const int w = tid >> 6;
  const int lane = tid & 63;
  const int e = blockIdx.x >> 9;
  const int m0 = (blockIdx.x & 511) << 4;
  const int lin = e * NLIN_PE + (m0 >> 8);  // all 16 m share one line

  // ---- build B in lds[0..16KB): Tr group at g*256 + m*16, Ti at +8192 ----
  {
    const int m = tid & 15;
    const int g0 = (tid >> 4) * 2;
    const int col = (m0 + m) & (NCOL - 1);
    const float ky = traj[(lin * NCOL + col) * 2 + 1];
#pragma unroll
    for (int gg = 0; gg < 2; ++gg) {
      const int g = g0 + gg;
      short8 vr, vi;
#pragma unroll
      for (int j = 0; j < 8; ++j) {
        const int k = g * 8 + j;
        float sn, cs;
        __sincosf(ky * (float)((k & 127) - 64), &sn, &cs);
        vr[j] = (short)f2bf((k < 128) ? cs : sn);   // Tr col: [cos ; +sin]
        vi[j] = (short)f2bf((k < 128) ? -sn : cs);  // Ti col: [-sin ; cos]
      }
      *(short8*)(lds + g * 256 + m * 16) = vr;
      *(short8*)(lds + 8192 + g * 256 + m * 16) = vi;
    }
  }

  // ---- ex phase factors in registers: 8 (x,m) pairs per lane ----
  const int mloc = lane & 15;
  const int xsub = lane >> 4;
  float exr[2][4], exi[2][4];
  {
    const int col = (m0 + mloc) & (NCOL - 1);
    const float kx = traj[(lin * NCOL + col) * 2 + 0];
#pragma unroll
    for (int par = 0; par < 2; ++par) {
      const int xb = (w + par * 4) * 16 + xsub * 4;
#pragma unroll
      for (int r = 0; r < 4; ++r) {
        float sn, cs;
        __sincosf(kx * (float)(xb + r - 64), &sn, &cs);
        exr[par][r] = cs;
        exi[par][r] = -sn;
      }
    }
  }
  __syncthreads();

  // ---- hoist B fragments (conflict-free: lane*16 contiguous) ----
  short8 bfr[2][8];
#pragma unroll
  for (int ct = 0; ct < 2; ++ct)
#pragma unroll
    for (int kk = 0; kk < 8; ++kk)
      bfr[ct][kk] = *(const short8*)(lds + ct * 8192 + kk * 1024 + lane * 16);
  __syncthreads();  // all waves done reading B; region reused for A staging

  float kr[8], ki[8];
#pragma unroll
  for (int b = 0; b < 8; ++b) {
    kr[b] = 0.f;
    ki[b] = 0.f;
  }

  const unsigned short* Ae = A + e * (NTILE * 4096);
  char* Abuf = lds + w * 16384;  // my two private 8KB buffers

  // prologue: issue row-tile rt = w into buf0
  {
    const unsigned short* src = Ae + w * 4096 + lane * 8;
#pragma unroll
    for (int j = 0; j < 8; ++j)
      __builtin_amdgcn_global_load_lds(
          (const __attribute__((address_space(1))) unsigned int*)(src + j * 512),
          (__attribute__((address_space(3))) unsigned int*)(Abuf + j * 1024), 16,
          0, 0);
  }

#pragma unroll
  for (int i = 0; i < 16; ++i) {
    const int b = i >> 1;    // compile-time under full unroll
    const int par = i & 1;

    if (i < 15) {
      // WAR guard: ds_reads of iter i-1 (same buffer as tile i+1) must drain
      asm volatile("s_waitcnt lgkmcnt(0)" ::: "memory");
      const int rt = w + (i + 1) * 4;
      const unsigned short* src = Ae + rt * 4096 + lane * 8;
      char* dstb = Abuf + ((i + 1) & 1) * 8192;
#pragma unroll
      for (int j = 0; j < 8; ++j)
        __builtin_amdgcn_global_load_lds(
            (const __attribute__((address_space(1))) unsigned int*)(src + j * 512),
            (__attribute__((address_space(3))) unsigned int*)(dstb + j * 1024),
            16, 0, 0);
      asm volatile("s_waitcnt vmcnt(8)" ::: "memory");  // tile i landed
    } else {
      asm volatile("s_waitcnt vmcnt(0)" ::: "memory");
    }

    const char* abase = Abuf + (i & 1) * 8192 + lane * 16;
    short8 afr[8];
#pragma unroll
    for (int kk = 0; kk < 8; ++kk)
      afr[kk] = *(const short8*)(abase + kk * 1024);

    float4_t accR = {0.f, 0.f, 0.f, 0.f};
    float4_t accI = {0.f, 0.f, 0.f, 0.f};
#pragma unroll
    for (int kk = 0; kk < 8; ++kk) {
      accR = __builtin_amdgcn_mfma_f32_16x16x32_bf16(afr[kk], bfr[0][kk], accR,
                                                     0, 0, 0);
      accI = __builtin_amdgcn_mfma_f32_16x16x32_bf16(afr[kk], bfr[1][kk], accI,
                                                     0, 0, 0);
    }
    // fused x-phase fold: x = (rt&7)*16 + xsub*4 + r, rt&7 = w + par*4
#pragma unroll
    for (int r = 0; r < 4; ++r) {
      const float xr = exr[par][r];
      const float xi = exi[par][r];
      kr[b] += accR[r] * xr - accI[r] * xi;
      ki[b] += accR[r] * xi + accI[r] * xr;
    }
  }

  // ---- cross-wave combine ----
  __syncthreads();
  float* comb = (float*)lds;  // 4 KB reuse
#pragma unroll
  for (int b = 0; b < 8; ++b) {
    float r = kr[b], im = ki[b];
    r += __shfl_xor(r, 16, 64);
    r += __shfl_xor(r, 32, 64);
    im += __shfl_xor(im, 16, 64);
    im += __shfl_xor(im, 32, 64);
    if (lane < 16) {
      comb[((w * 16 + lane) * 8 + b) * 2 + 0] = r;
      comb[((w * 16 + lane) * 8 + b) * 2 + 1] = im;
    }
  }
  __syncthreads();
  {
    const int m_l = tid >> 4;
    const int b = (tid >> 1) & 7;
    const int ri = tid & 1;
    float v = 0.f;
#pragma unroll
    for (int ww = 0; ww < 4; ++ww) v += comb[((ww * 16 + m_l) * 8 + b) * 2 + ri];
    const int m = m0 + m_l;
    const int col = m & (NCOL - 1);
    const int s = b >> 2;
    const float mv = mask[(s * NLIN + lin) * NCOL + col];
    out[((b * NLIN + lin) * NCOL + col) * 2 + ri] = v * mv;
  }
}

extern "C" void kernel_launch(void* const* d_in, const int* in_sizes, int n_in,
                              void* d_out, int out_size, void* d_ws, size_t ws_size,
                              hipStream_t stream) {
  const float* imR = (const float*)d_in[0];
  const float* imI = (const float*)d_in[1];
  const float* smR = (const float*)d_in[2];
  const float* smI = (const float*)d_in[3];
  const float* Dm = (const float*)d_in[4];
  const float* mask = (const float*)d_in[5];
  const float* traj = (const float*)d_in[6];
  float* out = (float*)d_out;
  unsigned short* A = (unsigned short*)d_ws;  // 2 MB: [ETL][64 tiles][32 g][16 r][8 j]

  prep_coil<<<dim3(NSLC * NX * NY / 256), dim3(256), 0, stream>>>(imR, imI, smR,
                                                                  smI, Dm, A);
  radtse_mfma<<<dim3(ETL * 512), dim3(256), 0, stream>>>(A, traj, mask, out);
}